// Round 1
// baseline (963.653 us; speedup 1.0000x reference)
//
#include <hip/hip_runtime.h>

// RNN-T Joint network, MI355X (gfx950)
// B=8 T=200 U=100 D=512 J=512 V=1024
// out[b,t,u,v] = sum_j tanh(enc_proj[b,t,j] + dec_proj[b,u,j]) * W_out[v,j] + b_out[v]

#define B_ 8
#define T_ 200
#define U_ 100
#define J_ 512
#define V_ 1024
#define M2_ (B_ * T_ * U_)   // 160000

typedef __attribute__((ext_vector_type(4))) float float4v;
typedef __attribute__((ext_vector_type(8))) short short8;
typedef __attribute__((ext_vector_type(4))) float f32x4;

#define DEV static __device__ __forceinline__

DEV unsigned short f2bf(float f) {
  // round-to-nearest-even fp32 -> bf16 (no NaN inputs here)
  unsigned int u = __float_as_uint(f);
  u += 0x7FFFu + ((u >> 16) & 1u);
  return (unsigned short)(u >> 16);
}

DEV short8 pack8(float4v a, float4v b) {
  short8 r;
  r[0] = (short)f2bf(a[0]); r[1] = (short)f2bf(a[1]);
  r[2] = (short)f2bf(a[2]); r[3] = (short)f2bf(a[3]);
  r[4] = (short)f2bf(b[0]); r[5] = (short)f2bf(b[1]);
  r[6] = (short)f2bf(b[2]); r[7] = (short)f2bf(b[3]);
  return r;
}

DEV float fast_tanh(float x) {
  // tanh(x) = 1 - 2/(exp(2x)+1); abs err ~1e-7, handles +-inf gracefully
  float t = __expf(2.0f * x);
  float r = __builtin_amdgcn_rcpf(t + 1.0f);
  return __builtin_fmaf(-2.0f, r, 1.0f);
}

// XOR-swizzled LDS addressing for [rows][64 bf16] tiles (row stride 128B):
// granule (16B) kb in [0,8) stored at physical kb ^ (row&7)  (T2-style, G4)
#define SWZ(base, row, kb) ((base) + ((row) << 7) + ((((kb) ^ ((row) & 7))) << 4))

// ---------------------------------------------------------------------------
// Kernel 1: W_out fp32 -> bf16  (1024x512 -> 1MB)
// ---------------------------------------------------------------------------
__global__ __launch_bounds__(256) void convert_wout(
    const float* __restrict__ W, unsigned short* __restrict__ Wb) {
  int i = blockIdx.x * 256 + threadIdx.x;          // 65536 threads, 8 elems each
  const float* p = W + (size_t)i * 8;
  float4v a = *(const float4v*)p;
  float4v b = *(const float4v*)(p + 4);
  *(short8*)(Wb + (size_t)i * 8) = pack8(a, b);
}

// ---------------------------------------------------------------------------
// Kernel 2: projections via bf16 MFMA.  blocks 0..199: enc (1600x512 @ W_enc^T
// + b_enc); blocks 200..303: dec (800x512 @ W_dec^T).  BM=BN=BK=64, 4 waves.
// ---------------------------------------------------------------------------
__global__ __launch_bounds__(256) void proj_kernel(
    const float* __restrict__ enc_out, const float* __restrict__ dec_out,
    const float* __restrict__ W_enc, const float* __restrict__ b_enc,
    const float* __restrict__ W_dec,
    float* __restrict__ enc_proj, float* __restrict__ dec_proj) {
  __shared__ char lds[16384];
  char* Albs = lds;
  char* Blbs = lds + 8192;

  int bid = blockIdx.x;
  bool is_enc = bid < 200;
  const float* srcA;
  const float* Wsrc;
  float* dst;
  int Mrows, bm, bn;
  if (is_enc) {
    bm = bid >> 3; bn = bid & 7;
    srcA = enc_out; Wsrc = W_enc; dst = enc_proj; Mrows = 1600;
  } else {
    int q = bid - 200;
    bm = q >> 3; bn = q & 7;
    srcA = dec_out; Wsrc = W_dec; dst = dec_proj; Mrows = 800;
  }

  int t = threadIdx.x;
  int l = t & 63;
  int w = t >> 6;
  int wrow = w >> 1, wcol = w & 1;

  f32x4 acc[2][2] = {};

  for (int k0 = 0; k0 < 512; k0 += 64) {
#pragma unroll
    for (int i = 0; i < 2; ++i) {
      int g = t + i * 256;               // granule id 0..511
      int row = g >> 3, kb = g & 7;
      int arow = bm * 64 + row;
      if (arow >= Mrows) arow = Mrows - 1;
      const float* pa = srcA + (size_t)arow * 512 + k0 + kb * 8;
      *(short8*)SWZ(Albs, row, kb) =
          pack8(*(const float4v*)pa, *(const float4v*)(pa + 4));
      const float* pb = Wsrc + (size_t)(bn * 64 + row) * 512 + k0 + kb * 8;
      *(short8*)SWZ(Blbs, row, kb) =
          pack8(*(const float4v*)pb, *(const float4v*)(pb + 4));
    }
    __syncthreads();
#pragma unroll
    for (int h = 0; h < 2; ++h) {
      int kb = h * 4 + (l >> 4);
      short8 af[2], bfv[2];
#pragma unroll
      for (int m = 0; m < 2; ++m) {
        int row = wrow * 32 + m * 16 + (l & 15);
        af[m] = *(const short8*)SWZ(Albs, row, kb);
      }
#pragma unroll
      for (int n = 0; n < 2; ++n) {
        int row = wcol * 32 + n * 16 + (l & 15);
        bfv[n] = *(const short8*)SWZ(Blbs, row, kb);
      }
#pragma unroll
      for (int m = 0; m < 2; ++m)
#pragma unroll
        for (int n = 0; n < 2; ++n)
          acc[m][n] = __builtin_amdgcn_mfma_f32_16x16x32_bf16(
              af[m], bfv[n], acc[m][n], 0, 0, 0);
    }
    __syncthreads();
  }

#pragma unroll
  for (int n = 0; n < 2; ++n) {
    int col = bn * 64 + wcol * 32 + n * 16 + (l & 15);
    float bias = is_enc ? b_enc[col] : 0.0f;
#pragma unroll
    for (int m = 0; m < 2; ++m) {
#pragma unroll
      for (int j = 0; j < 4; ++j) {
        int gr = bm * 64 + wrow * 32 + m * 16 + (l >> 4) * 4 + j;
        if (gr < Mrows) dst[(size_t)gr * 512 + col] = acc[m][n][j] + bias;
      }
    }
  }
}

// ---------------------------------------------------------------------------
// Kernel 3: fused tanh-joint GEMM.  M=160000, N=1024, K=512.
// BM=128 BN=128 BK=64, 256 threads (4 waves, each 64x64 = 4x4 frags).
// A generated on the fly: tanh(enc_proj[row] + dec_proj[row]) -> bf16 -> LDS.
// B staged with global_load_lds (pre-swizzled source, swizzled reads).
// ---------------------------------------------------------------------------
__global__ __launch_bounds__(256) void joint_kernel(
    const float* __restrict__ enc_proj, const float* __restrict__ dec_proj,
    const unsigned short* __restrict__ Wb, const float* __restrict__ b_out,
    float* __restrict__ out) {
  __shared__ char lds[32768];
  char* Albs = lds;            // A tile: 128 rows x 64 bf16 (swizzled)
  char* Blbs = lds + 16384;    // B tile: 128 cols x 64 bf16 (swizzled)

  int bid = blockIdx.x;
  int bm = bid >> 3;           // 0..1249  (M / 128)
  int bn = bid & 7;            // 0..7     (N / 128)

  int t = threadIdx.x;
  int l = t & 63;
  int w = t >> 6;
  int wrow = w >> 1, wcol = w & 1;

  // precompute per-thread A-staging row decompositions (constant over K-loop)
  int erow[4], drow[4];
  int kbA = t & 7;
#pragma unroll
  for (int i = 0; i < 4; ++i) {
    int row = (t >> 3) + i * 32;        // 0..127
    int gr = bm * 128 + row;            // global (b,t,u) row
    int b_ = gr / 20000;                // T*U = 20000
    int rem = gr - b_ * 20000;
    int u_ = rem % 100;
    erow[i] = gr / 100;                 // = b*T + t
    drow[i] = b_ * 100 + u_;            // = b*U + u
  }

  f32x4 acc[4][4] = {};

  for (int k0 = 0; k0 < 512; k0 += 64) {
    // ---- B staging: 4 granules/thread via global_load_lds (linear LDS dest,
    //      pre-swizzled global source)
#pragma unroll
    for (int i = 0; i < 4; ++i) {
      int g = t + i * 256;
      int row = g >> 3;                  // W_out column block row (0..127)
      int kbp = g & 7;                   // physical granule
      int kb = kbp ^ (row & 7);          // logical granule to fetch
      const unsigned short* src =
          Wb + (size_t)(bn * 128 + row) * 512 + k0 + kb * 8;
      __builtin_amdgcn_global_load_lds(
          (const __attribute__((address_space(1))) unsigned int*)src,
          (__attribute__((address_space(3))) unsigned int*)(Blbs + (w * 64 + i * 256) * 16),
          16, 0, 0);
    }
    // ---- A staging: load fp32 proj pair, tanh, pack bf16, swizzled ds_write
#pragma unroll
    for (int i = 0; i < 4; ++i) {
      int row = (t >> 3) + i * 32;
      const float* pe = enc_proj + (size_t)erow[i] * 512 + k0 + kbA * 8;
      const float* pd = dec_proj + (size_t)drow[i] * 512 + k0 + kbA * 8;
      float4v e0 = *(const float4v*)pe;
      float4v e1 = *(const float4v*)(pe + 4);
      float4v d0 = *(const float4v*)pd;
      float4v d1 = *(const float4v*)(pd + 4);
      float4v j0, j1;
#pragma unroll
      for (int q = 0; q < 4; ++q) {
        j0[q] = fast_tanh(e0[q] + d0[q]);
        j1[q] = fast_tanh(e1[q] + d1[q]);
      }
      *(short8*)SWZ(Albs, row, kbA) = pack8(j0, j1);
    }
    __syncthreads();

    // ---- MFMA: 2 k-halves x 4m x 4n
#pragma unroll
    for (int h = 0; h < 2; ++h) {
      int kb = h * 4 + (l >> 4);
      short8 af[4], bfv[4];
#pragma unroll
      for (int m = 0; m < 4; ++m) {
        int row = wrow * 64 + m * 16 + (l & 15);
        af[m] = *(const short8*)SWZ(Albs, row, kb);
      }
#pragma unroll
      for (int n = 0; n < 4; ++n) {
        int row = wcol * 64 + n * 16 + (l & 15);
        bfv[n] = *(const short8*)SWZ(Blbs, row, kb);
      }
#pragma unroll
      for (int m = 0; m < 4; ++m)
#pragma unroll
        for (int n = 0; n < 4; ++n)
          acc[m][n] = __builtin_amdgcn_mfma_f32_16x16x32_bf16(
              af[m], bfv[n], acc[m][n], 0, 0, 0);
    }
    __syncthreads();
  }

  // ---- epilogue: + b_out, store fp32
  int colbase = bn * 128 + wcol * 64;
#pragma unroll
  for (int n = 0; n < 4; ++n) {
    int col = colbase + n * 16 + (l & 15);
    float bias = b_out[col];
#pragma unroll
    for (int m = 0; m < 4; ++m) {
      int grb = bm * 128 + wrow * 64 + m * 16 + (l >> 4) * 4;
#pragma unroll
      for (int j = 0; j < 4; ++j) {
        out[(size_t)(grb + j) * 1024 + col] = acc[m][n][j] + bias;
      }
    }
  }
}

// ---------------------------------------------------------------------------
extern "C" void kernel_launch(void* const* d_in, const int* in_sizes, int n_in,
                              void* d_out, int out_size, void* d_ws, size_t ws_size,
                              hipStream_t stream) {
  const float* enc_out = (const float*)d_in[0];
  const float* dec_out = (const float*)d_in[1];
  const float* W_enc   = (const float*)d_in[2];
  const float* b_enc   = (const float*)d_in[3];
  const float* W_dec   = (const float*)d_in[4];
  const float* W_out   = (const float*)d_in[5];
  const float* b_out   = (const float*)d_in[6];
  float* out = (float*)d_out;

  char* ws = (char*)d_ws;
  float* enc_proj = (float*)ws;                               // 1600*512*4 = 3276800 B
  float* dec_proj = (float*)(ws + 3276800);                   //  800*512*4 = 1638400 B
  unsigned short* Wb = (unsigned short*)(ws + 3276800 + 1638400);  // 1024*512*2 = 1 MB

  hipLaunchKernelGGL(convert_wout, dim3(256), dim3(256), 0, stream, W_out, Wb);
  hipLaunchKernelGGL(proj_kernel, dim3(304), dim3(256), 0, stream,
                     enc_out, dec_out, W_enc, b_enc, W_dec, enc_proj, dec_proj);
  hipLaunchKernelGGL(joint_kernel, dim3((M2_ / 128) * 8), dim3(256), 0, stream,
                     enc_proj, dec_proj, Wb, b_out, out);
}

// Round 3
// 856.732 us; speedup vs baseline: 1.1248x; 1.1248x over previous
//
#include <hip/hip_runtime.h>

// RNN-T Joint network, MI355X (gfx950)
// B=8 T=200 U=100 D=512 J=512 V=1024
// out[b,t,u,v] = sum_j tanh(enc_proj[b,t,j] + dec_proj[b,u,j]) * W_out[v,j] + b_out[v]
//
// joint_kernel v2: A-strip (128 rows x 512 K, bf16) resident in LDS, tanh
// computed ONCE per element (was 8x). Loop 8 N-tiles x 8 K-steps; B tile
// double-buffered via global_load_lds (linear dest + pre-swizzled source,
// swizzled reads). LDS = 128K (A) + 2x16K (B) = 160KB, 1 block/CU, 8 waves.

#define B_ 8
#define T_ 200
#define U_ 100
#define J_ 512
#define V_ 1024
#define M2_ (B_ * T_ * U_)   // 160000

typedef __attribute__((ext_vector_type(4))) float float4v;
typedef __attribute__((ext_vector_type(8))) short short8;
typedef __attribute__((ext_vector_type(4))) float f32x4;

#define DEV static __device__ __forceinline__

DEV unsigned short f2bf(float f) {
  unsigned int u = __float_as_uint(f);
  u += 0x7FFFu + ((u >> 16) & 1u);
  return (unsigned short)(u >> 16);
}

DEV short8 pack8(float4v a, float4v b) {
  short8 r;
  r[0] = (short)f2bf(a[0]); r[1] = (short)f2bf(a[1]);
  r[2] = (short)f2bf(a[2]); r[3] = (short)f2bf(a[3]);
  r[4] = (short)f2bf(b[0]); r[5] = (short)f2bf(b[1]);
  r[6] = (short)f2bf(b[2]); r[7] = (short)f2bf(b[3]);
  return r;
}

DEV float fast_tanh(float x) {
  float t = __expf(2.0f * x);
  float r = __builtin_amdgcn_rcpf(t + 1.0f);
  return __builtin_fmaf(-2.0f, r, 1.0f);
}

// ---------------------------------------------------------------------------
// Kernel 1: W_out fp32 -> bf16  (1024x512 -> 1MB)
// ---------------------------------------------------------------------------
__global__ __launch_bounds__(256) void convert_wout(
    const float* __restrict__ W, unsigned short* __restrict__ Wb) {
  int i = blockIdx.x * 256 + threadIdx.x;
  const float* p = W + (size_t)i * 8;
  float4v a = *(const float4v*)p;
  float4v b = *(const float4v*)(p + 4);
  *(short8*)(Wb + (size_t)i * 8) = pack8(a, b);
}

// ---------------------------------------------------------------------------
// Kernel 2: projections via bf16 MFMA (unchanged from r1; ~fast).
// blocks 0..199: enc (1600x512 @ W_enc^T + b_enc); 200..303: dec (800x512).
// ---------------------------------------------------------------------------
#define SWZ64(base, row, kb) ((base) + ((row) << 7) + ((((kb) ^ ((row) & 7))) << 4))

__global__ __launch_bounds__(256) void proj_kernel(
    const float* __restrict__ enc_out, const float* __restrict__ dec_out,
    const float* __restrict__ W_enc, const float* __restrict__ b_enc,
    const float* __restrict__ W_dec,
    float* __restrict__ enc_proj, float* __restrict__ dec_proj) {
  __shared__ char lds[16384];
  char* Albs = lds;
  char* Blbs = lds + 8192;

  int bid = blockIdx.x;
  bool is_enc = bid < 200;
  const float* srcA;
  const float* Wsrc;
  float* dst;
  int Mrows, bm, bn;
  if (is_enc) {
    bm = bid >> 3; bn = bid & 7;
    srcA = enc_out; Wsrc = W_enc; dst = enc_proj; Mrows = 1600;
  } else {
    int q = bid - 200;
    bm = q >> 3; bn = q & 7;
    srcA = dec_out; Wsrc = W_dec; dst = dec_proj; Mrows = 800;
  }

  int t = threadIdx.x;
  int l = t & 63;
  int w = t >> 6;
  int wrow = w >> 1, wcol = w & 1;

  f32x4 acc[2][2] = {};

  for (int k0 = 0; k0 < 512; k0 += 64) {
#pragma unroll
    for (int i = 0; i < 2; ++i) {
      int g = t + i * 256;
      int row = g >> 3, kb = g & 7;
      int arow = bm * 64 + row;
      if (arow >= Mrows) arow = Mrows - 1;
      const float* pa = srcA + (size_t)arow * 512 + k0 + kb * 8;
      *(short8*)SWZ64(Albs, row, kb) =
          pack8(*(const float4v*)pa, *(const float4v*)(pa + 4));
      const float* pb = Wsrc + (size_t)(bn * 64 + row) * 512 + k0 + kb * 8;
      *(short8*)SWZ64(Blbs, row, kb) =
          pack8(*(const float4v*)pb, *(const float4v*)(pb + 4));
    }
    __syncthreads();
#pragma unroll
    for (int h = 0; h < 2; ++h) {
      int kb = h * 4 + (l >> 4);
      short8 af[2], bfv[2];
#pragma unroll
      for (int m = 0; m < 2; ++m) {
        int row = wrow * 32 + m * 16 + (l & 15);
        af[m] = *(const short8*)SWZ64(Albs, row, kb);
      }
#pragma unroll
      for (int n = 0; n < 2; ++n) {
        int row = wcol * 32 + n * 16 + (l & 15);
        bfv[n] = *(const short8*)SWZ64(Blbs, row, kb);
      }
#pragma unroll
      for (int m = 0; m < 2; ++m)
#pragma unroll
        for (int n = 0; n < 2; ++n)
          acc[m][n] = __builtin_amdgcn_mfma_f32_16x16x32_bf16(
              af[m], bfv[n], acc[m][n], 0, 0, 0);
    }
    __syncthreads();
  }

#pragma unroll
  for (int n = 0; n < 2; ++n) {
    int col = bn * 64 + wcol * 32 + n * 16 + (l & 15);
    float bias = is_enc ? b_enc[col] : 0.0f;
#pragma unroll
    for (int m = 0; m < 2; ++m) {
#pragma unroll
      for (int j = 0; j < 4; ++j) {
        int gr = bm * 64 + wrow * 32 + m * 16 + (l >> 4) * 4 + j;
        if (gr < Mrows) dst[(size_t)gr * 512 + col] = acc[m][n][j] + bias;
      }
    }
  }
}

// ---------------------------------------------------------------------------
// Kernel 3: fused tanh-joint GEMM, A-strip-resident version.
// Grid 1250 blocks (BM=128), 512 threads (8 waves: 2 wrow x 4 wcol).
// Wave tile 64 rows x 32 cols per N-tile; 8 N-tiles of 128 cols.
// ---------------------------------------------------------------------------
__global__ __launch_bounds__(512) void joint_kernel(
    const float* __restrict__ enc_proj, const float* __restrict__ dec_proj,
    const unsigned short* __restrict__ Wb, const float* __restrict__ b_out,
    float* __restrict__ out) {
  __shared__ char lds[163840];
  char* Astrip = lds;                    // 128 rows x 64 granules(16B), swizzled
  char* Bbuf0 = lds + 131072;            // 16KB: 128 cols x 8 granules, swizzled
  char* Bbuf1 = lds + 131072 + 16384;

  int bm = blockIdx.x;                   // 0..1249
  int t = threadIdx.x;
  int l = t & 63;
  int w = t >> 6;
  int wrow = w >> 2;                     // 0..1  (64-row half)
  int wcol = w & 3;                      // 0..3  (32-col slice)

  // ---- issue B[0] prefetch first (overlaps with A-gen)
  {
#pragma unroll
    for (int i = 0; i < 2; ++i) {
      int g = t + i * 512;
      int rowc = g >> 3;
      int kbp = g & 7;
      int kb = kbp ^ (rowc & 7);
      const unsigned short* src = Wb + (size_t)rowc * 512 + kb * 8;  // nt=0,k0=0
      __builtin_amdgcn_global_load_lds(
          (const __attribute__((address_space(1))) unsigned int*)src,
          (__attribute__((address_space(3))) unsigned int*)(Bbuf0 + g * 16),
          16, 0, 0);
    }
  }

  // ---- A-strip generation: tanh(enc+dec) -> bf16, swizzled, ONCE
  {
    int row = t >> 2;                    // 0..127 (4 threads per row)
    int gr = bm * 128 + row;
    int b_ = gr / 20000;                 // T*U
    int rem = gr - b_ * 20000;
    int u_ = rem % 100;
    int erow = gr / 100;
    int drow = b_ * 100 + u_;
    const float* pe_base = enc_proj + (size_t)erow * 512;
    const float* pd_base = dec_proj + (size_t)drow * 512;
    char* arow_base = Astrip + row * 1024;
    int swz = row & 7;
#pragma unroll
    for (int i = 0; i < 16; ++i) {
      int kb = i * 4 + (t & 3);          // granule 0..63
      const float* pe = pe_base + kb * 8;
      const float* pd = pd_base + kb * 8;
      float4v e0 = *(const float4v*)pe;
      float4v e1 = *(const float4v*)(pe + 4);
      float4v d0 = *(const float4v*)pd;
      float4v d1 = *(const float4v*)(pd + 4);
      float4v j0, j1;
#pragma unroll
      for (int q = 0; q < 4; ++q) {
        j0[q] = fast_tanh(e0[q] + d0[q]);
        j1[q] = fast_tanh(e1[q] + d1[q]);
      }
      *(short8*)(arow_base + ((kb ^ swz) << 4)) = pack8(j0, j1);
    }
  }
  __syncthreads();   // A-strip complete; B[0] landed (drains vmcnt+lgkmcnt)

  f32x4 acc[4][2] = {{{0.f,0.f,0.f,0.f}}};
#pragma unroll
  for (int m = 0; m < 4; ++m)
#pragma unroll
    for (int n = 0; n < 2; ++n)
      acc[m][n] = (f32x4){0.f, 0.f, 0.f, 0.f};

  // ---- main loop: 64 steps = 8 N-tiles x 8 K-steps (BK=64)
  for (int s = 0; s < 64; ++s) {
    char* Bcur = (s & 1) ? Bbuf1 : Bbuf0;
    char* Bnxt = (s & 1) ? Bbuf0 : Bbuf1;

    // prefetch B[s+1] into the other buffer
    if (s < 63) {
      int nt1 = (s + 1) >> 3;
      int k01 = ((s + 1) & 7) * 64;
#pragma unroll
      for (int i = 0; i < 2; ++i) {
        int g = t + i * 512;
        int rowc = g >> 3;
        int kbp = g & 7;
        int kb = kbp ^ (rowc & 7);
        const unsigned short* src =
            Wb + (size_t)(nt1 * 128 + rowc) * 512 + k01 + kb * 8;
        __builtin_amdgcn_global_load_lds(
            (const __attribute__((address_space(1))) unsigned int*)src,
            (__attribute__((address_space(3))) unsigned int*)(Bnxt + g * 16),
            16, 0, 0);
      }
    }

    int k0g = (s & 7) * 8;               // A granule base for this K-step
#pragma unroll
    for (int kk = 0; kk < 2; ++kk) {
      short8 af[4], bfv[2];
      int kbA = k0g + kk * 4 + (l >> 4);
#pragma unroll
      for (int m = 0; m < 4; ++m) {
        int r = wrow * 64 + m * 16 + (l & 15);
        af[m] = *(const short8*)(Astrip + r * 1024 + (((kbA ^ (r & 7))) << 4));
      }
      int kbB = kk * 4 + (l >> 4);
#pragma unroll
      for (int n = 0; n < 2; ++n) {
        int rc = wcol * 32 + n * 16 + (l & 15);
        bfv[n] = *(const short8*)(Bcur + rc * 128 + (((kbB ^ (rc & 7))) << 4));
      }
      __builtin_amdgcn_s_setprio(1);
#pragma unroll
      for (int m = 0; m < 4; ++m)
#pragma unroll
        for (int n = 0; n < 2; ++n)
          acc[m][n] = __builtin_amdgcn_mfma_f32_16x16x32_bf16(
              af[m], bfv[n], acc[m][n], 0, 0, 0);
      __builtin_amdgcn_s_setprio(0);
    }

    // epilogue at end of each N-tile
    if ((s & 7) == 7) {
      int nt = s >> 3;
#pragma unroll
      for (int n = 0; n < 2; ++n) {
        int col = nt * 128 + wcol * 32 + n * 16 + (l & 15);
        float bias = b_out[col];
#pragma unroll
        for (int m = 0; m < 4; ++m) {
          int r0 = bm * 128 + wrow * 64 + m * 16 + (l >> 4) * 4;
#pragma unroll
          for (int j = 0; j < 4; ++j)
            out[(size_t)(r0 + j) * 1024 + col] = acc[m][n][j] + bias;
          acc[m][n] = (f32x4){0.f, 0.f, 0.f, 0.f};
        }
      }
    }

    __syncthreads();   // B[s+1] landed for all waves; Bcur free for overwrite
  }
}

// ---------------------------------------------------------------------------
extern "C" void kernel_launch(void* const* d_in, const int* in_sizes, int n_in,
                              void* d_out, int out_size, void* d_ws, size_t ws_size,
                              hipStream_t stream) {
  const float* enc_out = (const float*)d_in[0];
  const float* dec_out = (const float*)d_in[1];
  const float* W_enc   = (const float*)d_in[2];
  const float* b_enc   = (const float*)d_in[3];
  const float* W_dec   = (const float*)d_in[4];
  const float* W_out   = (const float*)d_in[5];
  const float* b_out   = (const float*)d_in[6];
  float* out = (float*)d_out;

  char* ws = (char*)d_ws;
  float* enc_proj = (float*)ws;                                   // 3276800 B
  float* dec_proj = (float*)(ws + 3276800);                       // 1638400 B
  unsigned short* Wb = (unsigned short*)(ws + 3276800 + 1638400); // 1 MB

  hipLaunchKernelGGL(convert_wout, dim3(256), dim3(256), 0, stream, W_out, Wb);
  hipLaunchKernelGGL(proj_kernel, dim3(304), dim3(256), 0, stream,
                     enc_out, dec_out, W_enc, b_enc, W_dec, enc_proj, dec_proj);
  hipLaunchKernelGGL(joint_kernel, dim3(M2_ / 128), dim3(512), 0, stream,
                     enc_proj, dec_proj, Wb, b_out, out);
}

// Round 4
// 839.211 us; speedup vs baseline: 1.1483x; 1.0209x over previous
//
#include <hip/hip_runtime.h>

// RNN-T Joint network, MI355X (gfx950)
// B=8 T=200 U=100 D=512 J=512 V=1024
// out[b,t,u,v] = sum_j tanh(enc_proj[b,t,j] + dec_proj[b,u,j]) * W_out[v,j] + b_out[v]
//
// joint_kernel v3: barrier-free main loop.
//  - A-strip (128 rows x 512 K, bf16) in LDS, TRANSPOSED As[g][row] so MFMA
//    fragment reads are contiguous per 16-lane group (conflict-free, no swizzle).
//  - B (W_out bf16) TRANSPOSED in global Wbt[g][col]; fragments loaded directly
//    L2->VGPR with coalesced global_load_dwordx4 (no LDS staging, no barriers).
//  - 8 waves = 2 row-groups x 4 col-groups; wave tile 64x64 (4m x 4n frags);
//    4 N-passes of 256 cols. Single __syncthreads after A-gen.

#define B_ 8
#define T_ 200
#define U_ 100
#define J_ 512
#define V_ 1024
#define M2_ (B_ * T_ * U_)   // 160000

typedef __attribute__((ext_vector_type(4))) float float4v;
typedef __attribute__((ext_vector_type(8))) short short8;
typedef __attribute__((ext_vector_type(4))) float f32x4;

#define DEV static __device__ __forceinline__

DEV unsigned short f2bf(float f) {
  unsigned int u = __float_as_uint(f);
  u += 0x7FFFu + ((u >> 16) & 1u);
  return (unsigned short)(u >> 16);
}

DEV short8 pack8(float4v a, float4v b) {
  short8 r;
  r[0] = (short)f2bf(a[0]); r[1] = (short)f2bf(a[1]);
  r[2] = (short)f2bf(a[2]); r[3] = (short)f2bf(a[3]);
  r[4] = (short)f2bf(b[0]); r[5] = (short)f2bf(b[1]);
  r[6] = (short)f2bf(b[2]); r[7] = (short)f2bf(b[3]);
  return r;
}

DEV float fast_tanh(float x) {
  float t = __expf(2.0f * x);
  float r = __builtin_amdgcn_rcpf(t + 1.0f);
  return __builtin_fmaf(-2.0f, r, 1.0f);
}

// ---------------------------------------------------------------------------
// Kernel 1: W_out fp32 [1024][512] -> bf16 TRANSPOSED Wbt[g][col][8]
// (g = K-granule of 8 bf16, 64 granules; col = output vocab 0..1023)
// ---------------------------------------------------------------------------
__global__ __launch_bounds__(256) void convert_wout(
    const float* __restrict__ W, unsigned short* __restrict__ Wbt) {
  int i = blockIdx.x * 256 + threadIdx.x;   // 65536 threads
  int col = i & 1023;
  int g = i >> 10;                           // 0..63
  const float* p = W + (size_t)col * 512 + g * 8;
  float4v a = *(const float4v*)p;
  float4v b = *(const float4v*)(p + 4);
  // consecutive threads (same g, col+1) -> consecutive 16B: coalesced writes
  *(short8*)(Wbt + (size_t)g * 8192 + col * 8) = pack8(a, b);
}

// ---------------------------------------------------------------------------
// Kernel 2: projections via bf16 MFMA (unchanged).
// blocks 0..199: enc (1600x512 @ W_enc^T + b_enc); 200..303: dec (800x512).
// ---------------------------------------------------------------------------
#define SWZ64(base, row, kb) ((base) + ((row) << 7) + ((((kb) ^ ((row) & 7))) << 4))

__global__ __launch_bounds__(256) void proj_kernel(
    const float* __restrict__ enc_out, const float* __restrict__ dec_out,
    const float* __restrict__ W_enc, const float* __restrict__ b_enc,
    const float* __restrict__ W_dec,
    float* __restrict__ enc_proj, float* __restrict__ dec_proj) {
  __shared__ char lds[16384];
  char* Albs = lds;
  char* Blbs = lds + 8192;

  int bid = blockIdx.x;
  bool is_enc = bid < 200;
  const float* srcA;
  const float* Wsrc;
  float* dst;
  int Mrows, bm, bn;
  if (is_enc) {
    bm = bid >> 3; bn = bid & 7;
    srcA = enc_out; Wsrc = W_enc; dst = enc_proj; Mrows = 1600;
  } else {
    int q = bid - 200;
    bm = q >> 3; bn = q & 7;
    srcA = dec_out; Wsrc = W_dec; dst = dec_proj; Mrows = 800;
  }

  int t = threadIdx.x;
  int l = t & 63;
  int w = t >> 6;
  int wrow = w >> 1, wcol = w & 1;

  f32x4 acc[2][2] = {};

  for (int k0 = 0; k0 < 512; k0 += 64) {
#pragma unroll
    for (int i = 0; i < 2; ++i) {
      int g = t + i * 256;
      int row = g >> 3, kb = g & 7;
      int arow = bm * 64 + row;
      if (arow >= Mrows) arow = Mrows - 1;
      const float* pa = srcA + (size_t)arow * 512 + k0 + kb * 8;
      *(short8*)SWZ64(Albs, row, kb) =
          pack8(*(const float4v*)pa, *(const float4v*)(pa + 4));
      const float* pb = Wsrc + (size_t)(bn * 64 + row) * 512 + k0 + kb * 8;
      *(short8*)SWZ64(Blbs, row, kb) =
          pack8(*(const float4v*)pb, *(const float4v*)(pb + 4));
    }
    __syncthreads();
#pragma unroll
    for (int h = 0; h < 2; ++h) {
      int kb = h * 4 + (l >> 4);
      short8 af[2], bfv[2];
#pragma unroll
      for (int m = 0; m < 2; ++m) {
        int row = wrow * 32 + m * 16 + (l & 15);
        af[m] = *(const short8*)SWZ64(Albs, row, kb);
      }
#pragma unroll
      for (int n = 0; n < 2; ++n) {
        int row = wcol * 32 + n * 16 + (l & 15);
        bfv[n] = *(const short8*)SWZ64(Blbs, row, kb);
      }
#pragma unroll
      for (int m = 0; m < 2; ++m)
#pragma unroll
        for (int n = 0; n < 2; ++n)
          acc[m][n] = __builtin_amdgcn_mfma_f32_16x16x32_bf16(
              af[m], bfv[n], acc[m][n], 0, 0, 0);
    }
    __syncthreads();
  }

#pragma unroll
  for (int n = 0; n < 2; ++n) {
    int col = bn * 64 + wcol * 32 + n * 16 + (l & 15);
    float bias = is_enc ? b_enc[col] : 0.0f;
#pragma unroll
    for (int m = 0; m < 2; ++m) {
#pragma unroll
      for (int j = 0; j < 4; ++j) {
        int gr = bm * 64 + wrow * 32 + m * 16 + (l >> 4) * 4 + j;
        if (gr < Mrows) dst[(size_t)gr * 512 + col] = acc[m][n][j] + bias;
      }
    }
  }
}

// ---------------------------------------------------------------------------
// Kernel 3: fused tanh-joint GEMM, barrier-free.
// Grid 1250 blocks (BM=128), 512 threads (8 waves: 2 wrow x 4 wcol).
// ---------------------------------------------------------------------------
__global__ __launch_bounds__(512, 2) void joint_kernel(
    const float* __restrict__ enc_proj, const float* __restrict__ dec_proj,
    const unsigned short* __restrict__ Wbt, const float* __restrict__ b_out,
    float* __restrict__ out) {
  // A-strip transposed: As[g][row], g in [0,64) granules of 8 bf16, row in [0,128)
  // byte addr = g*2048 + row*16.  128 KB.
  __shared__ char As[131072];

  int bm = blockIdx.x;                   // 0..1249
  int t = threadIdx.x;
  int l = t & 63;
  int w = t >> 6;
  int wrow = w >> 2;                     // 0..1  (64-row half)
  int wcol = w & 3;                      // 0..3  (64-col quarter of the pass)
  int lr = l & 15;
  int lg = l >> 4;

  // ---- A-strip generation: tanh(enc+dec) -> bf16 -> As[g][row], ONCE
  {
    int row = t & 127;
    int gbase = t >> 7;                  // 0..3
    int gr = bm * 128 + row;
    int b_ = gr / 20000;                 // T*U
    int rem = gr - b_ * 20000;
    int u_ = rem % 100;
    int erow = gr / 100;                 // b*T + t
    int drow = b_ * 100 + u_;            // b*U + u
    const float* pe_base = enc_proj + (size_t)erow * 512;
    const float* pd_base = dec_proj + (size_t)drow * 512;
#pragma unroll
    for (int i = 0; i < 16; ++i) {
      int g = gbase + i * 4;             // granule 0..63
      const float* pe = pe_base + g * 8;
      const float* pd = pd_base + g * 8;
      float4v e0 = *(const float4v*)pe;
      float4v e1 = *(const float4v*)(pe + 4);
      float4v d0 = *(const float4v*)pd;
      float4v d1 = *(const float4v*)(pd + 4);
      float4v j0, j1;
#pragma unroll
      for (int q = 0; q < 4; ++q) {
        j0[q] = fast_tanh(e0[q] + d0[q]);
        j1[q] = fast_tanh(e1[q] + d1[q]);
      }
      // contiguous 16B per thread; 16-lane groups write contiguous 256B
      *(short8*)(As + g * 2048 + row * 16) = pack8(j0, j1);
    }
  }
  __syncthreads();   // the ONLY block-wide barrier

  // ---- 4 N-passes of 256 cols; wave tile 64 rows x 64 cols (4m x 4n)
  for (int np = 0; np < 4; ++np) {
    int colbase = np * 256 + wcol * 64;
    float bias[4];
#pragma unroll
    for (int n = 0; n < 4; ++n) bias[n] = b_out[colbase + n * 16 + lr];

    f32x4 acc[4][4];
#pragma unroll
    for (int m = 0; m < 4; ++m)
#pragma unroll
      for (int n = 0; n < 4; ++n)
        acc[m][n] = (f32x4){0.f, 0.f, 0.f, 0.f};

#pragma unroll 2
    for (int ks = 0; ks < 8; ++ks) {
#pragma unroll
      for (int kk = 0; kk < 2; ++kk) {
        int g = ks * 8 + kk * 4 + lg;    // K-granule for this fragment
        short8 af[4], bfv[4];
#pragma unroll
        for (int n = 0; n < 4; ++n) {
          int c = colbase + n * 16 + lr;
          // lanes 0-15 consecutive cols -> contiguous 256B: coalesced
          bfv[n] = *(const short8*)(Wbt + (size_t)g * 8192 + c * 8);
        }
#pragma unroll
        for (int m = 0; m < 4; ++m) {
          int r = wrow * 64 + m * 16 + lr;
          af[m] = *(const short8*)(As + g * 2048 + r * 16);
        }
        __builtin_amdgcn_s_setprio(1);
#pragma unroll
        for (int m = 0; m < 4; ++m)
#pragma unroll
          for (int n = 0; n < 4; ++n)
            acc[m][n] = __builtin_amdgcn_mfma_f32_16x16x32_bf16(
                af[m], bfv[n], acc[m][n], 0, 0, 0);
        __builtin_amdgcn_s_setprio(0);
      }
    }

    // ---- epilogue for this pass: + b_out, store fp32
#pragma unroll
    for (int n = 0; n < 4; ++n) {
      int col = colbase + n * 16 + lr;
#pragma unroll
      for (int m = 0; m < 4; ++m) {
        int r0 = bm * 128 + wrow * 64 + m * 16 + lg * 4;
#pragma unroll
        for (int j = 0; j < 4; ++j)
          out[(size_t)(r0 + j) * 1024 + col] = acc[m][n][j] + bias[n];
      }
    }
  }
}

// ---------------------------------------------------------------------------
extern "C" void kernel_launch(void* const* d_in, const int* in_sizes, int n_in,
                              void* d_out, int out_size, void* d_ws, size_t ws_size,
                              hipStream_t stream) {
  const float* enc_out = (const float*)d_in[0];
  const float* dec_out = (const float*)d_in[1];
  const float* W_enc   = (const float*)d_in[2];
  const float* b_enc   = (const float*)d_in[3];
  const float* W_dec   = (const float*)d_in[4];
  const float* W_out   = (const float*)d_in[5];
  const float* b_out   = (const float*)d_in[6];
  float* out = (float*)d_out;

  char* ws = (char*)d_ws;
  float* enc_proj = (float*)ws;                                   // 3276800 B
  float* dec_proj = (float*)(ws + 3276800);                       // 1638400 B
  unsigned short* Wbt = (unsigned short*)(ws + 3276800 + 1638400); // 1 MB

  hipLaunchKernelGGL(convert_wout, dim3(256), dim3(256), 0, stream, W_out, Wbt);
  hipLaunchKernelGGL(proj_kernel, dim3(304), dim3(256), 0, stream,
                     enc_out, dec_out, W_enc, b_enc, W_dec, enc_proj, dec_proj);
  hipLaunchKernelGGL(joint_kernel, dim3(M2_ / 128), dim3(512), 0, stream,
                     enc_proj, dec_proj, Wbt, b_out, out);
}